// Round 1
// baseline (104.622 us; speedup 1.0000x reference)
//
#include <hip/hip_runtime.h>
#include <math.h>

#define D_SINGLE 512
#define D_PAIR   128
#define RANK     32
#define NROW     512
#define EPS      1e-5f

// ---------------------------------------------------------------------------
// Kernel 1: per-row LayerNorm + low-rank projection for both inputs.
// grid = 1024 blocks (0..511 -> single_a/w_left, 512..1023 -> single_b/w_right)
// block = 256 threads (4 waves)
// ---------------------------------------------------------------------------
__global__ __launch_bounds__(256) void k1_ln_proj(
    const float* __restrict__ xa, const float* __restrict__ xb,
    const float* __restrict__ ln_g, const float* __restrict__ ln_b,
    const float* __restrict__ wl, const float* __restrict__ bl,
    const float* __restrict__ wr, const float* __restrict__ br,
    float* __restrict__ a_proj, float* __restrict__ b_proj)
{
    const int bid  = blockIdx.x;
    const int row  = bid & (NROW - 1);
    const bool isb = bid >= NROW;
    const float* x    = (isb ? xb : xa) + row * D_SINGLE;
    const float* W    = isb ? wr : wl;
    const float* bias = isb ? br : bl;
    float* out        = (isb ? b_proj : a_proj) + row * RANK;

    __shared__ float xn[D_SINGLE];
    __shared__ float red[8];

    const int t    = threadIdx.x;
    const int wave = t >> 6;
    const int lane = t & 63;

    float x0 = x[t], x1 = x[t + 256];
    float s  = x0 + x1;
    float ss = x0 * x0 + x1 * x1;
    #pragma unroll
    for (int m = 1; m < 64; m <<= 1) {
        s  += __shfl_xor(s, m);
        ss += __shfl_xor(ss, m);
    }
    if (lane == 0) { red[wave] = s; red[4 + wave] = ss; }
    __syncthreads();
    float S    = red[0] + red[1] + red[2] + red[3];
    float SS   = red[4] + red[5] + red[6] + red[7];
    float mean = S * (1.0f / D_SINGLE);
    float var  = SS * (1.0f / D_SINGLE) - mean * mean;
    float rstd = rsqrtf(var + EPS);
    xn[t]       = (x0 - mean) * rstd * ln_g[t]       + ln_b[t];
    xn[t + 256] = (x1 - mean) * rstd * ln_g[t + 256] + ln_b[t + 256];
    __syncthreads();

    // wave w computes outputs r = w + 4*q, q = 0..7
    #pragma unroll
    for (int q = 0; q < 8; ++q) {
        int r = wave + 4 * q;
        float acc = 0.f;
        #pragma unroll
        for (int tt = 0; tt < 8; ++tt) {
            int k = lane + 64 * tt;
            acc += xn[k] * W[r * D_SINGLE + k];
        }
        #pragma unroll
        for (int m = 1; m < 64; m <<= 1) acc += __shfl_xor(acc, m);
        if (lane == 0) out[r] = acc + bias[r];
    }
}

// ---------------------------------------------------------------------------
// Kernel 2: wb[j][p][r] = sum_s b[j][s] * w_out[p][r*32+s]
// wb layout: [j][pr] with pr = p*32 + r  (r innermost, contiguous)
// grid = 64 j-groups * 16 pr-chunks = 1024 blocks; block = 256 threads.
// Each thread holds its 32-float w_out slice in regs and reuses it for 8 j.
// ---------------------------------------------------------------------------
__global__ __launch_bounds__(256) void k2_wb(
    const float* __restrict__ bproj, const float* __restrict__ w_out,
    float* __restrict__ wb)
{
    const int g = blockIdx.x >> 4;   // j-group (8 rows of b)
    const int c = blockIdx.x & 15;   // pr chunk
    const int t = threadIdx.x;

    __shared__ float bl[8 * RANK];   // 8 rows of b
    bl[t] = bproj[g * 8 * RANK + t];
    __syncthreads();

    const int pr = c * 256 + t;
    const int p  = pr >> 5;
    const int r  = pr & 31;

    const float4* wrow = reinterpret_cast<const float4*>(w_out + p * (RANK * RANK) + r * RANK);
    float4 w[8];
    #pragma unroll
    for (int q = 0; q < 8; ++q) w[q] = wrow[q];

    #pragma unroll
    for (int jj = 0; jj < 8; ++jj) {
        float acc = 0.f;
        #pragma unroll
        for (int q = 0; q < 8; ++q) {
            acc += bl[jj * 32 + 4 * q + 0] * w[q].x
                 + bl[jj * 32 + 4 * q + 1] * w[q].y
                 + bl[jj * 32 + 4 * q + 2] * w[q].z
                 + bl[jj * 32 + 4 * q + 3] * w[q].w;
        }
        wb[(size_t)(g * 8 + jj) * 4096 + pr] = acc;
    }
}

// ---------------------------------------------------------------------------
// Kernel 3: out[i][j][p] = LN_p( sum_r a[i][r]*wb[j][p][r] + b_out[p] )
// grid = 4096 blocks: j = bid & 511 (fast), chunk = bid >> 9 (64 i-rows each)
// block = 256 threads = 4 waves; wave w handles 16 rows.
// Lane l owns p = l and p = l+64: wb slices live in 64 VGPRs.
// LN reduction is a pure in-wave shfl_xor reduce (p fully covered by wave).
// ---------------------------------------------------------------------------
__global__ __launch_bounds__(256) void k3_main(
    const float* __restrict__ a, const float* __restrict__ wb,
    const float* __restrict__ b_out, const float* __restrict__ lno_g,
    const float* __restrict__ lno_b, float* __restrict__ out)
{
    const int j     = blockIdx.x & (NROW - 1);
    const int chunk = blockIdx.x >> 9;      // 0..7, 64 rows each
    const int t     = threadIdx.x;
    const int wave  = t >> 6;
    const int lane  = t & 63;

    __shared__ __align__(16) float a_lds[64 * RANK];  // 8 KB

    // stage this chunk's 64 a-rows
    #pragma unroll
    for (int q = 0; q < 8; ++q)
        a_lds[t + 256 * q] = a[chunk * 64 * RANK + t + 256 * q];

    // per-lane wb slices: p = lane and p = lane+64
    const float4* wbp = reinterpret_cast<const float4*>(wb + (size_t)j * 4096);
    float4 w0[8], w1[8];
    #pragma unroll
    for (int q = 0; q < 8; ++q) {
        w0[q] = wbp[lane * 8 + q];
        w1[q] = wbp[(lane + 64) * 8 + q];
    }
    const float bo0 = b_out[lane], bo1 = b_out[lane + 64];
    const float g0  = lno_g[lane], g1  = lno_g[lane + 64];
    const float be0 = lno_b[lane], be1 = lno_b[lane + 64];
    __syncthreads();

    const float4* a4 = reinterpret_cast<const float4*>(a_lds);

    #pragma unroll 4
    for (int n = 0; n < 16; ++n) {
        const int iloc = wave * 16 + n;
        float v0 = bo0, v1 = bo1;
        #pragma unroll
        for (int q = 0; q < 8; ++q) {
            float4 av = a4[iloc * 8 + q];   // broadcast read (all lanes same addr)
            v0 += av.x * w0[q].x + av.y * w0[q].y + av.z * w0[q].z + av.w * w0[q].w;
            v1 += av.x * w1[q].x + av.y * w1[q].y + av.z * w1[q].z + av.w * w1[q].w;
        }
        float s  = v0 + v1;
        float ss = v0 * v0 + v1 * v1;
        #pragma unroll
        for (int m = 1; m < 64; m <<= 1) {
            s  += __shfl_xor(s, m);
            ss += __shfl_xor(ss, m);
        }
        const float mean = s * (1.0f / D_PAIR);
        const float var  = ss * (1.0f / D_PAIR) - mean * mean;
        const float rstd = rsqrtf(var + EPS);
        const int i = chunk * 64 + iloc;
        float* o = out + ((size_t)i * NROW + j) * D_PAIR;
        o[lane]      = (v0 - mean) * rstd * g0 + be0;
        o[lane + 64] = (v1 - mean) * rstd * g1 + be1;
    }
}

// ---------------------------------------------------------------------------
extern "C" void kernel_launch(void* const* d_in, const int* in_sizes, int n_in,
                              void* d_out, int out_size, void* d_ws, size_t ws_size,
                              hipStream_t stream) {
    const float* single_a = (const float*)d_in[0];
    const float* single_b = (const float*)d_in[1];
    const float* ln_g     = (const float*)d_in[2];
    const float* ln_b     = (const float*)d_in[3];
    const float* w_left   = (const float*)d_in[4];
    const float* b_left   = (const float*)d_in[5];
    const float* w_right  = (const float*)d_in[6];
    const float* b_right  = (const float*)d_in[7];
    const float* w_out    = (const float*)d_in[8];
    const float* b_out    = (const float*)d_in[9];
    const float* lno_g    = (const float*)d_in[10];
    const float* lno_b    = (const float*)d_in[11];
    float* out = (float*)d_out;

    float* ws     = (float*)d_ws;
    float* a_proj = ws;                    // 512*32
    float* b_proj = ws + NROW * RANK;      // 512*32
    float* wb     = ws + 2 * NROW * RANK;  // 512*4096 floats = 8 MB

    k1_ln_proj<<<2 * NROW, 256, 0, stream>>>(single_a, single_b, ln_g, ln_b,
                                             w_left, b_left, w_right, b_right,
                                             a_proj, b_proj);
    k2_wb<<<1024, 256, 0, stream>>>(b_proj, w_out, wb);
    k3_main<<<4096, 256, 0, stream>>>(a_proj, wb, b_out, lno_g, lno_b, out);
}

// Round 2
// 91.220 us; speedup vs baseline: 1.1469x; 1.1469x over previous
//
#include <hip/hip_runtime.h>
#include <math.h>

#define D_SINGLE 512
#define D_PAIR   128
#define RANK     32
#define NROW     512
#define EPS      1e-5f

// ---------------------------------------------------------------------------
// Kernel 1: per-row LayerNorm + low-rank projection for both inputs.
// ---------------------------------------------------------------------------
__global__ __launch_bounds__(256) void k1_ln_proj(
    const float* __restrict__ xa, const float* __restrict__ xb,
    const float* __restrict__ ln_g, const float* __restrict__ ln_b,
    const float* __restrict__ wl, const float* __restrict__ bl,
    const float* __restrict__ wr, const float* __restrict__ br,
    float* __restrict__ a_proj, float* __restrict__ b_proj)
{
    const int bid  = blockIdx.x;
    const int row  = bid & (NROW - 1);
    const bool isb = bid >= NROW;
    const float* x    = (isb ? xb : xa) + row * D_SINGLE;
    const float* W    = isb ? wr : wl;
    const float* bias = isb ? br : bl;
    float* out        = (isb ? b_proj : a_proj) + row * RANK;

    __shared__ float xn[D_SINGLE];
    __shared__ float red[8];

    const int t    = threadIdx.x;
    const int wave = t >> 6;
    const int lane = t & 63;

    float x0 = x[t], x1 = x[t + 256];
    float s  = x0 + x1;
    float ss = x0 * x0 + x1 * x1;
    #pragma unroll
    for (int m = 1; m < 64; m <<= 1) {
        s  += __shfl_xor(s, m);
        ss += __shfl_xor(ss, m);
    }
    if (lane == 0) { red[wave] = s; red[4 + wave] = ss; }
    __syncthreads();
    float S    = red[0] + red[1] + red[2] + red[3];
    float SS   = red[4] + red[5] + red[6] + red[7];
    float mean = S * (1.0f / D_SINGLE);
    float var  = SS * (1.0f / D_SINGLE) - mean * mean;
    float rstd = rsqrtf(var + EPS);
    xn[t]       = (x0 - mean) * rstd * ln_g[t]       + ln_b[t];
    xn[t + 256] = (x1 - mean) * rstd * ln_g[t + 256] + ln_b[t + 256];
    __syncthreads();

    #pragma unroll
    for (int q = 0; q < 8; ++q) {
        int r = wave + 4 * q;
        float acc = 0.f;
        #pragma unroll
        for (int tt = 0; tt < 8; ++tt) {
            int k = lane + 64 * tt;
            acc += xn[k] * W[r * D_SINGLE + k];
        }
        #pragma unroll
        for (int m = 1; m < 64; m <<= 1) acc += __shfl_xor(acc, m);
        if (lane == 0) out[r] = acc + bias[r];
    }
}

// ---------------------------------------------------------------------------
// Kernel 2: wb[j][p*32+r] = sum_s b[j][s] * w_out[p][r*32+s]
// ---------------------------------------------------------------------------
__global__ __launch_bounds__(256) void k2_wb(
    const float* __restrict__ bproj, const float* __restrict__ w_out,
    float* __restrict__ wb)
{
    const int g = blockIdx.x >> 4;   // j-group (8 rows of b)
    const int c = blockIdx.x & 15;   // pr chunk
    const int t = threadIdx.x;

    __shared__ float bl[8 * RANK];
    bl[t] = bproj[g * 8 * RANK + t];
    __syncthreads();

    const int pr = c * 256 + t;
    const int p  = pr >> 5;
    const int r  = pr & 31;

    const float4* wrow = reinterpret_cast<const float4*>(w_out + p * (RANK * RANK) + r * RANK);
    float4 w[8];
    #pragma unroll
    for (int q = 0; q < 8; ++q) w[q] = wrow[q];

    #pragma unroll
    for (int jj = 0; jj < 8; ++jj) {
        float acc = 0.f;
        #pragma unroll
        for (int q = 0; q < 8; ++q) {
            acc += bl[jj * 32 + 4 * q + 0] * w[q].x
                 + bl[jj * 32 + 4 * q + 1] * w[q].y
                 + bl[jj * 32 + 4 * q + 2] * w[q].z
                 + bl[jj * 32 + 4 * q + 3] * w[q].w;
        }
        wb[(size_t)(g * 8 + jj) * 4096 + pr] = acc;
    }
}

// ---------------------------------------------------------------------------
// Kernel 3: out[i][j][p] = LN_p( sum_r a[i][r]*wb[j][p][r] + b_out[p] )
// __launch_bounds__(256, 2): VGPR cap 256 so the 64-float wb slice stays
// register-resident (round-1 failure: default cap 64 VGPRs -> reloads).
// Rows processed in pairs: 4 independent FMA chains.
// ---------------------------------------------------------------------------
__global__ __launch_bounds__(256, 2) void k3_main(
    const float* __restrict__ a, const float* __restrict__ wb,
    const float* __restrict__ b_out, const float* __restrict__ lno_g,
    const float* __restrict__ lno_b, float* __restrict__ out)
{
    const int j     = blockIdx.x & (NROW - 1);
    const int chunk = blockIdx.x >> 9;      // 0..7, 64 i-rows each
    const int t     = threadIdx.x;
    const int wave  = t >> 6;
    const int lane  = t & 63;

    __shared__ __align__(16) float a_lds[64 * RANK];  // 8 KB

    #pragma unroll
    for (int q = 0; q < 8; ++q)
        a_lds[t + 256 * q] = a[chunk * 64 * RANK + t + 256 * q];

    const float4* wbp = reinterpret_cast<const float4*>(wb + (size_t)j * 4096);
    float4 w0[8], w1[8];
    #pragma unroll
    for (int q = 0; q < 8; ++q) {
        w0[q] = wbp[lane * 8 + q];
        w1[q] = wbp[(lane + 64) * 8 + q];
    }
    const float bo0 = b_out[lane], bo1 = b_out[lane + 64];
    const float g0  = lno_g[lane], g1  = lno_g[lane + 64];
    const float be0 = lno_b[lane], be1 = lno_b[lane + 64];
    __syncthreads();

    const float4* a4 = reinterpret_cast<const float4*>(a_lds);

    #pragma unroll 2
    for (int n = 0; n < 16; n += 2) {
        const int iA = wave * 16 + n;
        const int iB = iA + 1;
        float v0a = bo0, v1a = bo1, v0b = bo0, v1b = bo1;
        #pragma unroll
        for (int q = 0; q < 8; ++q) {
            float4 avA = a4[iA * 8 + q];   // broadcast LDS read
            float4 avB = a4[iB * 8 + q];
            v0a += avA.x * w0[q].x + avA.y * w0[q].y + avA.z * w0[q].z + avA.w * w0[q].w;
            v1a += avA.x * w1[q].x + avA.y * w1[q].y + avA.z * w1[q].z + avA.w * w1[q].w;
            v0b += avB.x * w0[q].x + avB.y * w0[q].y + avB.z * w0[q].z + avB.w * w0[q].w;
            v1b += avB.x * w1[q].x + avB.y * w1[q].y + avB.z * w1[q].z + avB.w * w1[q].w;
        }
        float sa  = v0a + v1a, sb  = v0b + v1b;
        float ssa = v0a * v0a + v1a * v1a;
        float ssb = v0b * v0b + v1b * v1b;
        #pragma unroll
        for (int m = 1; m < 64; m <<= 1) {
            sa  += __shfl_xor(sa, m);
            ssa += __shfl_xor(ssa, m);
            sb  += __shfl_xor(sb, m);
            ssb += __shfl_xor(ssb, m);
        }
        const float meana = sa * (1.0f / D_PAIR);
        const float vara  = ssa * (1.0f / D_PAIR) - meana * meana;
        const float rstda = rsqrtf(vara + EPS);
        const float meanb = sb * (1.0f / D_PAIR);
        const float varb  = ssb * (1.0f / D_PAIR) - meanb * meanb;
        const float rstdb = rsqrtf(varb + EPS);

        float* oA = out + (((size_t)(chunk * 64 + iA)) * NROW + j) * D_PAIR;
        float* oB = out + (((size_t)(chunk * 64 + iB)) * NROW + j) * D_PAIR;
        oA[lane]      = (v0a - meana) * rstda * g0 + be0;
        oA[lane + 64] = (v1a - meana) * rstda * g1 + be1;
        oB[lane]      = (v0b - meanb) * rstdb * g0 + be0;
        oB[lane + 64] = (v1b - meanb) * rstdb * g1 + be1;
    }
}

// ---------------------------------------------------------------------------
extern "C" void kernel_launch(void* const* d_in, const int* in_sizes, int n_in,
                              void* d_out, int out_size, void* d_ws, size_t ws_size,
                              hipStream_t stream) {
    const float* single_a = (const float*)d_in[0];
    const float* single_b = (const float*)d_in[1];
    const float* ln_g     = (const float*)d_in[2];
    const float* ln_b     = (const float*)d_in[3];
    const float* w_left   = (const float*)d_in[4];
    const float* b_left   = (const float*)d_in[5];
    const float* w_right  = (const float*)d_in[6];
    const float* b_right  = (const float*)d_in[7];
    const float* w_out    = (const float*)d_in[8];
    const float* b_out    = (const float*)d_in[9];
    const float* lno_g    = (const float*)d_in[10];
    const float* lno_b    = (const float*)d_in[11];
    float* out = (float*)d_out;

    float* ws     = (float*)d_ws;
    float* a_proj = ws;                    // 512*32
    float* b_proj = ws + NROW * RANK;      // 512*32
    float* wb     = ws + 2 * NROW * RANK;  // 512*4096 floats = 8 MB

    k1_ln_proj<<<2 * NROW, 256, 0, stream>>>(single_a, single_b, ln_g, ln_b,
                                             w_left, b_left, w_right, b_right,
                                             a_proj, b_proj);
    k2_wb<<<1024, 256, 0, stream>>>(b_proj, w_out, wb);
    k3_main<<<4096, 256, 0, stream>>>(a_proj, wb, b_out, lno_g, lno_b, out);
}

// Round 3
// 90.961 us; speedup vs baseline: 1.1502x; 1.0028x over previous
//
#include <hip/hip_runtime.h>
#include <math.h>

#define D_SINGLE 512
#define D_PAIR   128
#define RANK     32
#define NROW     512
#define EPS      1e-5f

// ---------------------------------------------------------------------------
// Kernel 1: per-row LayerNorm + low-rank projection for both inputs.
// ---------------------------------------------------------------------------
__global__ __launch_bounds__(256) void k1_ln_proj(
    const float* __restrict__ xa, const float* __restrict__ xb,
    const float* __restrict__ ln_g, const float* __restrict__ ln_b,
    const float* __restrict__ wl, const float* __restrict__ bl,
    const float* __restrict__ wr, const float* __restrict__ br,
    float* __restrict__ a_proj, float* __restrict__ b_proj)
{
    const int bid  = blockIdx.x;
    const int row  = bid & (NROW - 1);
    const bool isb = bid >= NROW;
    const float* x    = (isb ? xb : xa) + row * D_SINGLE;
    const float* W    = isb ? wr : wl;
    const float* bias = isb ? br : bl;
    float* out        = (isb ? b_proj : a_proj) + row * RANK;

    __shared__ float xn[D_SINGLE];
    __shared__ float red[8];

    const int t    = threadIdx.x;
    const int wave = t >> 6;
    const int lane = t & 63;

    float x0 = x[t], x1 = x[t + 256];
    float s  = x0 + x1;
    float ss = x0 * x0 + x1 * x1;
    #pragma unroll
    for (int m = 1; m < 64; m <<= 1) {
        s  += __shfl_xor(s, m);
        ss += __shfl_xor(ss, m);
    }
    if (lane == 0) { red[wave] = s; red[4 + wave] = ss; }
    __syncthreads();
    float S    = red[0] + red[1] + red[2] + red[3];
    float SS   = red[4] + red[5] + red[6] + red[7];
    float mean = S * (1.0f / D_SINGLE);
    float var  = SS * (1.0f / D_SINGLE) - mean * mean;
    float rstd = rsqrtf(var + EPS);
    xn[t]       = (x0 - mean) * rstd * ln_g[t]       + ln_b[t];
    xn[t + 256] = (x1 - mean) * rstd * ln_g[t + 256] + ln_b[t + 256];
    __syncthreads();

    #pragma unroll
    for (int q = 0; q < 8; ++q) {
        int r = wave + 4 * q;
        float acc = 0.f;
        #pragma unroll
        for (int tt = 0; tt < 8; ++tt) {
            int k = lane + 64 * tt;
            acc += xn[k] * W[r * D_SINGLE + k];
        }
        #pragma unroll
        for (int m = 1; m < 64; m <<= 1) acc += __shfl_xor(acc, m);
        if (lane == 0) out[r] = acc + bias[r];
    }
}

// ---------------------------------------------------------------------------
// Kernel 2: wb[j][p*32+r] = sum_s b[j][s] * w_out[p][r*32+s]
// ---------------------------------------------------------------------------
__global__ __launch_bounds__(256) void k2_wb(
    const float* __restrict__ bproj, const float* __restrict__ w_out,
    float* __restrict__ wb)
{
    const int g = blockIdx.x >> 4;   // j-group (8 rows of b)
    const int c = blockIdx.x & 15;   // pr chunk
    const int t = threadIdx.x;

    __shared__ float bl[8 * RANK];
    bl[t] = bproj[g * 8 * RANK + t];
    __syncthreads();

    const int pr = c * 256 + t;
    const int p  = pr >> 5;
    const int r  = pr & 31;

    const float4* wrow = reinterpret_cast<const float4*>(w_out + p * (RANK * RANK) + r * RANK);
    float4 w[8];
    #pragma unroll
    for (int q = 0; q < 8; ++q) w[q] = wrow[q];

    #pragma unroll
    for (int jj = 0; jj < 8; ++jj) {
        float acc = 0.f;
        #pragma unroll
        for (int q = 0; q < 8; ++q) {
            acc += bl[jj * 32 + 4 * q + 0] * w[q].x
                 + bl[jj * 32 + 4 * q + 1] * w[q].y
                 + bl[jj * 32 + 4 * q + 2] * w[q].z
                 + bl[jj * 32 + 4 * q + 3] * w[q].w;
        }
        wb[(size_t)(g * 8 + jj) * 4096 + pr] = acc;
    }
}

// ---------------------------------------------------------------------------
// Kernel 3: out[i][j][p] = LN_p( sum_r a[i][r]*wb[j][p][r] + b_out[p] )
// Round-2 failure: compiler sank the loop-invariant wb loads into the row
// loop (VGPR_Count=52 < the 64 floats of the slice) -> per-iteration L1/L2
// refetch. Fix: asm-pin the loaded values so they cannot be rematerialized.
// ---------------------------------------------------------------------------
__global__ __launch_bounds__(256, 2) void k3_main(
    const float* __restrict__ a, const float* __restrict__ wb,
    const float* __restrict__ b_out, const float* __restrict__ lno_g,
    const float* __restrict__ lno_b, float* __restrict__ out)
{
    const int j     = blockIdx.x & (NROW - 1);
    const int chunk = blockIdx.x >> 9;      // 0..7, 64 i-rows each
    const int t     = threadIdx.x;
    const int wave  = t >> 6;
    const int lane  = t & 63;

    __shared__ __align__(16) float a_lds[64 * RANK];  // 8 KB

    #pragma unroll
    for (int q = 0; q < 8; ++q)
        a_lds[t + 256 * q] = a[chunk * 64 * RANK + t + 256 * q];

    const float4* wbp = reinterpret_cast<const float4*>(wb + (size_t)j * 4096);
    float4 w0[8], w1[8];
    #pragma unroll
    for (int q = 0; q < 8; ++q) {
        w0[q] = wbp[lane * 8 + q];
        w1[q] = wbp[(lane + 64) * 8 + q];
    }
    // Pin the wb slice in VGPRs: the empty asm redefines each component, so
    // the compiler cannot sink/rematerialize the loads inside the row loop.
    #pragma unroll
    for (int q = 0; q < 8; ++q) {
        asm volatile("" : "+v"(w0[q].x), "+v"(w0[q].y), "+v"(w0[q].z), "+v"(w0[q].w));
        asm volatile("" : "+v"(w1[q].x), "+v"(w1[q].y), "+v"(w1[q].z), "+v"(w1[q].w));
    }
    const float bo0 = b_out[lane], bo1 = b_out[lane + 64];
    const float g0  = lno_g[lane], g1  = lno_g[lane + 64];
    const float be0 = lno_b[lane], be1 = lno_b[lane + 64];
    __syncthreads();

    const float4* a4 = reinterpret_cast<const float4*>(a_lds);

    #pragma unroll 2
    for (int n = 0; n < 16; n += 2) {
        const int iA = wave * 16 + n;
        const int iB = iA + 1;
        float v0a = bo0, v1a = bo1, v0b = bo0, v1b = bo1;
        #pragma unroll
        for (int q = 0; q < 8; ++q) {
            float4 avA = a4[iA * 8 + q];   // broadcast LDS read
            float4 avB = a4[iB * 8 + q];
            v0a += avA.x * w0[q].x + avA.y * w0[q].y + avA.z * w0[q].z + avA.w * w0[q].w;
            v1a += avA.x * w1[q].x + avA.y * w1[q].y + avA.z * w1[q].z + avA.w * w1[q].w;
            v0b += avB.x * w0[q].x + avB.y * w0[q].y + avB.z * w0[q].z + avB.w * w0[q].w;
            v1b += avB.x * w1[q].x + avB.y * w1[q].y + avB.z * w1[q].z + avB.w * w1[q].w;
        }
        float sa  = v0a + v1a, sb  = v0b + v1b;
        float ssa = v0a * v0a + v1a * v1a;
        float ssb = v0b * v0b + v1b * v1b;
        #pragma unroll
        for (int m = 1; m < 64; m <<= 1) {
            sa  += __shfl_xor(sa, m);
            ssa += __shfl_xor(ssa, m);
            sb  += __shfl_xor(sb, m);
            ssb += __shfl_xor(ssb, m);
        }
        const float meana = sa * (1.0f / D_PAIR);
        const float vara  = ssa * (1.0f / D_PAIR) - meana * meana;
        const float rstda = rsqrtf(vara + EPS);
        const float meanb = sb * (1.0f / D_PAIR);
        const float varb  = ssb * (1.0f / D_PAIR) - meanb * meanb;
        const float rstdb = rsqrtf(varb + EPS);

        float* oA = out + (((size_t)(chunk * 64 + iA)) * NROW + j) * D_PAIR;
        float* oB = out + (((size_t)(chunk * 64 + iB)) * NROW + j) * D_PAIR;
        oA[lane]      = (v0a - meana) * rstda * g0 + be0;
        oA[lane + 64] = (v1a - meana) * rstda * g1 + be1;
        oB[lane]      = (v0b - meanb) * rstdb * g0 + be0;
        oB[lane + 64] = (v1b - meanb) * rstdb * g1 + be1;
    }
}

// ---------------------------------------------------------------------------
extern "C" void kernel_launch(void* const* d_in, const int* in_sizes, int n_in,
                              void* d_out, int out_size, void* d_ws, size_t ws_size,
                              hipStream_t stream) {
    const float* single_a = (const float*)d_in[0];
    const float* single_b = (const float*)d_in[1];
    const float* ln_g     = (const float*)d_in[2];
    const float* ln_b     = (const float*)d_in[3];
    const float* w_left   = (const float*)d_in[4];
    const float* b_left   = (const float*)d_in[5];
    const float* w_right  = (const float*)d_in[6];
    const float* b_right  = (const float*)d_in[7];
    const float* w_out    = (const float*)d_in[8];
    const float* b_out    = (const float*)d_in[9];
    const float* lno_g    = (const float*)d_in[10];
    const float* lno_b    = (const float*)d_in[11];
    float* out = (float*)d_out;

    float* ws     = (float*)d_ws;
    float* a_proj = ws;                    // 512*32
    float* b_proj = ws + NROW * RANK;      // 512*32
    float* wb     = ws + 2 * NROW * RANK;  // 512*4096 floats = 8 MB

    k1_ln_proj<<<2 * NROW, 256, 0, stream>>>(single_a, single_b, ln_g, ln_b,
                                             w_left, b_left, w_right, b_right,
                                             a_proj, b_proj);
    k2_wb<<<1024, 256, 0, stream>>>(b_proj, w_out, wb);
    k3_main<<<4096, 256, 0, stream>>>(a_proj, wb, b_out, lno_g, lno_b, out);
}

// Round 4
// 56.407 us; speedup vs baseline: 1.8548x; 1.6126x over previous
//
#include <hip/hip_runtime.h>
#include <hip/hip_bf16.h>
#include <math.h>

#define D_SINGLE 512
#define D_PAIR   128
#define RANK     32
#define NROW     512
#define EPS      1e-5f

typedef __attribute__((ext_vector_type(8))) short bf16x8;  // 8 bf16 = 4 VGPRs
typedef __attribute__((ext_vector_type(4))) float f32x4;

// ---------------------------------------------------------------------------
// Kernel 1: per-row LayerNorm + low-rank projection for both inputs.
// a-side output stored as bf16 (feeds k3 MFMA B-frag), b-side as f32 (feeds k2).
// ---------------------------------------------------------------------------
__global__ __launch_bounds__(256) void k1_ln_proj(
    const float* __restrict__ xa, const float* __restrict__ xb,
    const float* __restrict__ ln_g, const float* __restrict__ ln_b,
    const float* __restrict__ wl, const float* __restrict__ bl,
    const float* __restrict__ wr, const float* __restrict__ br,
    __hip_bfloat16* __restrict__ a_bf, float* __restrict__ b_proj)
{
    const int bid  = blockIdx.x;
    const int row  = bid & (NROW - 1);
    const bool isb = bid >= NROW;
    const float* x    = (isb ? xb : xa) + row * D_SINGLE;
    const float* W    = isb ? wr : wl;
    const float* bias = isb ? br : bl;
    float*           outf = b_proj + row * RANK;
    __hip_bfloat16*  outh = a_bf   + row * RANK;

    __shared__ float xn[D_SINGLE];
    __shared__ float red[8];

    const int t    = threadIdx.x;
    const int wave = t >> 6;
    const int lane = t & 63;

    float x0 = x[t], x1 = x[t + 256];
    float s  = x0 + x1;
    float ss = x0 * x0 + x1 * x1;
    #pragma unroll
    for (int m = 1; m < 64; m <<= 1) {
        s  += __shfl_xor(s, m);
        ss += __shfl_xor(ss, m);
    }
    if (lane == 0) { red[wave] = s; red[4 + wave] = ss; }
    __syncthreads();
    float S    = red[0] + red[1] + red[2] + red[3];
    float SS   = red[4] + red[5] + red[6] + red[7];
    float mean = S * (1.0f / D_SINGLE);
    float var  = SS * (1.0f / D_SINGLE) - mean * mean;
    float rstd = rsqrtf(var + EPS);
    xn[t]       = (x0 - mean) * rstd * ln_g[t]       + ln_b[t];
    xn[t + 256] = (x1 - mean) * rstd * ln_g[t + 256] + ln_b[t + 256];
    __syncthreads();

    #pragma unroll
    for (int q = 0; q < 8; ++q) {
        int r = wave + 4 * q;
        float acc = 0.f;
        #pragma unroll
        for (int tt = 0; tt < 8; ++tt) {
            int k = lane + 64 * tt;
            acc += xn[k] * W[r * D_SINGLE + k];
        }
        #pragma unroll
        for (int m = 1; m < 64; m <<= 1) acc += __shfl_xor(acc, m);
        if (lane == 0) {
            float v = acc + bias[r];
            if (isb) outf[r] = v;
            else     outh[r] = __float2bfloat16(v);
        }
    }
}

// ---------------------------------------------------------------------------
// Kernel 2: wb[j][p*32+r] = sum_s b[j][s] * w_out[p][r*32+s], stored bf16.
// ---------------------------------------------------------------------------
__global__ __launch_bounds__(256) void k2_wb(
    const float* __restrict__ bproj, const float* __restrict__ w_out,
    __hip_bfloat16* __restrict__ wb)
{
    const int g = blockIdx.x >> 4;   // j-group (8 rows of b)
    const int c = blockIdx.x & 15;   // pr chunk
    const int t = threadIdx.x;

    __shared__ float bl[8 * RANK];
    bl[t] = bproj[g * 8 * RANK + t];
    __syncthreads();

    const int pr = c * 256 + t;
    const int p  = pr >> 5;
    const int r  = pr & 31;

    const float4* wrow = reinterpret_cast<const float4*>(w_out + p * (RANK * RANK) + r * RANK);
    float4 w[8];
    #pragma unroll
    for (int q = 0; q < 8; ++q) w[q] = wrow[q];

    #pragma unroll
    for (int jj = 0; jj < 8; ++jj) {
        float acc = 0.f;
        #pragma unroll
        for (int q = 0; q < 8; ++q) {
            acc += bl[jj * 32 + 4 * q + 0] * w[q].x
                 + bl[jj * 32 + 4 * q + 1] * w[q].y
                 + bl[jj * 32 + 4 * q + 2] * w[q].z
                 + bl[jj * 32 + 4 * q + 3] * w[q].w;
        }
        wb[(size_t)(g * 8 + jj) * 4096 + pr] = __float2bfloat16(acc);
    }
}

// ---------------------------------------------------------------------------
// Kernel 3 (MFMA): D[p,i] = WB_j[p,r] * a^T[r,i] + b_out[p], then LN over p.
// One wave per (j, 16-row i-block). 8 MFMAs cover p=0..127, K=32 in one shot.
// k-packing r=(lane>>4)*8+e used identically for A and B => layout-safe.
// C/D: row(p) = (lane>>4)*4+reg, col(i) = lane&15 (verified m89 mapping).
// LN over p: 32 in-register adds + shfl_xor(16) + shfl_xor(32). No LDS.
// ---------------------------------------------------------------------------
__global__ __launch_bounds__(256, 4) void k3_mfma(
    const __hip_bfloat16* __restrict__ a_bf, const __hip_bfloat16* __restrict__ wb_bf,
    const float* __restrict__ b_out, const float* __restrict__ lno_g,
    const float* __restrict__ lno_b, float* __restrict__ out)
{
    const int t    = threadIdx.x;
    const int wv   = t >> 6;
    const int lane = t & 63;
    const int g    = lane >> 4;
    const int c    = lane & 15;
    const int j      = blockIdx.x & (NROW - 1);
    const int iblock = (blockIdx.x >> 9) * 4 + wv;   // 0..31
    const int i0     = iblock * 16 + c;              // this lane's i (col)

    // B-frag: row i0 of a (32 bf16), k-slice g*8..g*8+7
    const short* a_s = reinterpret_cast<const short*>(a_bf);
    bf16x8 bfrag = *reinterpret_cast<const bf16x8*>(a_s + i0 * RANK + g * 8);

    // A-frags: WB_j[p][r], p = tile*16 + c, r = g*8..g*8+7 (16B each)
    const short* wbj = reinterpret_cast<const short*>(wb_bf) + (size_t)j * 4096;

    f32x4 acc[8];
    bf16x8 af[8];
    #pragma unroll
    for (int tt = 0; tt < 8; ++tt) {
        acc[tt] = *reinterpret_cast<const f32x4*>(b_out + tt * 16 + g * 4);  // C-in = bias
        af[tt]  = *reinterpret_cast<const bf16x8*>(wbj + (tt * 16 + c) * RANK + g * 8);
    }
    #pragma unroll
    for (int tt = 0; tt < 8; ++tt)
        acc[tt] = __builtin_amdgcn_mfma_f32_16x16x32_bf16(af[tt], bfrag, acc[tt], 0, 0, 0);

    // LN over p=128 for this lane's i
    float s = 0.f, ss = 0.f;
    #pragma unroll
    for (int tt = 0; tt < 8; ++tt) {
        #pragma unroll
        for (int r = 0; r < 4; ++r) { float v = acc[tt][r]; s += v; ss += v * v; }
    }
    s  += __shfl_xor(s, 16);  ss += __shfl_xor(ss, 16);
    s  += __shfl_xor(s, 32);  ss += __shfl_xor(ss, 32);
    const float mean = s * (1.0f / D_PAIR);
    const float var  = ss * (1.0f / D_PAIR) - mean * mean;
    const float rstd = rsqrtf(var + EPS);

    float* obase = out + ((size_t)i0 * NROW + j) * D_PAIR;
    #pragma unroll
    for (int tt = 0; tt < 8; ++tt) {
        f32x4 gm = *reinterpret_cast<const f32x4*>(lno_g + tt * 16 + g * 4);
        f32x4 bt = *reinterpret_cast<const f32x4*>(lno_b + tt * 16 + g * 4);
        f32x4 o;
        #pragma unroll
        for (int r = 0; r < 4; ++r)
            o[r] = (acc[tt][r] - mean) * rstd * gm[r] + bt[r];
        *reinterpret_cast<f32x4*>(obase + tt * 16 + g * 4) = o;
    }
}

// ---------------------------------------------------------------------------
extern "C" void kernel_launch(void* const* d_in, const int* in_sizes, int n_in,
                              void* d_out, int out_size, void* d_ws, size_t ws_size,
                              hipStream_t stream) {
    const float* single_a = (const float*)d_in[0];
    const float* single_b = (const float*)d_in[1];
    const float* ln_g     = (const float*)d_in[2];
    const float* ln_b     = (const float*)d_in[3];
    const float* w_left   = (const float*)d_in[4];
    const float* b_left   = (const float*)d_in[5];
    const float* w_right  = (const float*)d_in[6];
    const float* b_right  = (const float*)d_in[7];
    const float* w_out    = (const float*)d_in[8];
    const float* b_out    = (const float*)d_in[9];
    const float* lno_g    = (const float*)d_in[10];
    const float* lno_b    = (const float*)d_in[11];
    float* out = (float*)d_out;

    float* ws = (float*)d_ws;
    __hip_bfloat16* a_bf   = (__hip_bfloat16*)ws;                    // 512*32 bf16 = 32 KB
    float*          b_proj = ws + 16384;                             // 512*32 f32 (64 KB @ +64KB)
    __hip_bfloat16* wb_bf  = (__hip_bfloat16*)(ws + 32768);          // 512*4096 bf16 = 4 MB

    k1_ln_proj<<<2 * NROW, 256, 0, stream>>>(single_a, single_b, ln_g, ln_b,
                                             w_left, b_left, w_right, b_right,
                                             a_bf, b_proj);
    k2_wb<<<1024, 256, 0, stream>>>(b_proj, w_out, wb_bf);
    k3_mfma<<<4096, 256, 0, stream>>>(a_bf, wb_bf, b_out, lno_g, lno_b, out);
}